// Round 16
// baseline (118.514 us; speedup 1.0000x reference)
//
#include <hip/hip_runtime.h>
#include <hip/hip_bf16.h>
#include <math.h>

#define B_SZ 16384
#define C_SZ 2048
#define D_SZ 128
#define MAXP 256
#define SCAN_BLOCKS 4096

typedef float f32x4 __attribute__((ext_vector_type(4)));
typedef short short8 __attribute__((ext_vector_type(8)));

// ---- workspace layout (bytes) ----
// 0        : pos_count[C]     int   (8192)
// 8448     : pos_list[C*MAXP] int   (2 MB)   -> 2,105,600
// 2105600  : pnh [C*D] bf16 (512KB) -> 2,629,888
// 2629888  : pnl [C*D] bf16 (512KB) -> 3,154,176
// 3154176  : enh [C*D] bf16 (512KB) -> 3,678,464
// 3678464  : enl [C*D] bf16 (512KB) -> 4,202,752
// 4210944  : sim[C*C] f32 (16MB)    -> 20,988,160
// 20988160 : cosm[C*C] f32 (16MB)   -> 37,765,376
// 37765376 : partial[C*2] f32 (16KB)
// 41943040 : scratch for measurement-duplicate scan (pc2/pl2/enh2/enl2)

__global__ __launch_bounds__(256) void k_pre(unsigned* __restrict__ zr,
                                             unsigned* __restrict__ zr2) {
    int t = blockIdx.x * blockDim.x + threadIdx.x;
    if (t < C_SZ) { zr[t] = 0u; zr2[t] = 0u; }
}

// blocks 0..4095: scan targets -> pos lists (two-phase branchless).
// blocks 4096+: L2-normalize class_emb.
__global__ __launch_bounds__(256) void k_scan(const float* __restrict__ targets,
                                              const float* __restrict__ class_emb,
                                              int* __restrict__ pos_count,
                                              int* __restrict__ pos_list,
                                              __hip_bfloat16* __restrict__ enh,
                                              __hip_bfloat16* __restrict__ enl) {
    const int bid = blockIdx.x;
    if (bid >= SCAN_BLOCKS) {
        const int g = threadIdx.x >> 7;        // 0..1 class within block
        const int d = threadIdx.x & 127;
        const int c = ((bid - SCAN_BLOCKS) << 1) + g;
        __shared__ float s_w[2][2];
        float v = class_emb[c * D_SZ + d];
        float sq = v * v;
#pragma unroll
        for (int off = 32; off >= 1; off >>= 1) sq += __shfl_xor(sq, off);
        if ((d & 63) == 0) s_w[g][d >> 6] = sq;
        __syncthreads();
        float tot = s_w[g][0] + s_w[g][1];
        float vn = v * rsqrtf(tot + 1e-12f);
        __hip_bfloat16 h = __float2bfloat16(vn);
        enh[c * D_SZ + d] = h;
        enl[c * D_SZ + d] = __float2bfloat16(vn - __bfloat162float(h));
        return;
    }
    const int tid = bid * 256 + threadIdx.x;          // 0..1048575
    const int stride = SCAN_BLOCKS * 256;             // 1,048,576 float4s
    unsigned mask = 0u;
#pragma unroll
    for (int k = 0; k < 8; ++k) {
        float4 t = ((const float4*)targets)[tid + k * stride];
        unsigned m = (unsigned)(t.x != 0.f)
                   | ((unsigned)(t.y != 0.f) << 1)
                   | ((unsigned)(t.z != 0.f) << 2)
                   | ((unsigned)(t.w != 0.f) << 3);
        mask |= m << (k << 2);
    }
    while (mask) {
        int bit = __builtin_ctz(mask);
        mask &= mask - 1;
        int k = bit >> 2, q = bit & 3;
        int e0 = (tid + k * stride) << 2;
        int b = e0 >> 11;
        int c = (e0 & (C_SZ - 1)) + q;
        int slot = atomicAdd(&pos_count[c], 1);
        if ((unsigned)slot < (unsigned)MAXP) pos_list[c * MAXP + slot] = b;
    }
}

// masked mean pool + L2 norm -> pn(h,l). 256 thr/class, k-loop split in halves.
__global__ __launch_bounds__(256) void k_pool(const float* __restrict__ output,
                                              const int* __restrict__ pos_count,
                                              const int* __restrict__ pos_list,
                                              __hip_bfloat16* __restrict__ pnh,
                                              __hip_bfloat16* __restrict__ pnl) {
    int c = blockIdx.x;
    int d = threadIdx.x & 127;
    int half = threadIdx.x >> 7;
    __shared__ float s_acc[2][128];
    __shared__ float s_cnt[2][128];
    __shared__ float s_w[2];
    int n = pos_count[c];
    if (n > MAXP) n = MAXP;
    float acc = 0.f, cnt = 0.f;
    for (int k = half; k < n; k += 2) {
        int b = pos_list[c * MAXP + k];
        float v = output[b * D_SZ + d];
        acc += v;
        cnt += (v != 0.f) ? 1.f : 0.f;
    }
    s_acc[half][d] = acc;
    s_cnt[half][d] = cnt;
    __syncthreads();
    if (half == 0) {
        acc = s_acc[0][d] + s_acc[1][d];
        cnt = s_cnt[0][d] + s_cnt[1][d];
        float pooled = acc / (cnt + 1e-9f);
        float sq = pooled * pooled;
#pragma unroll
        for (int off = 32; off >= 1; off >>= 1) sq += __shfl_xor(sq, off);
        if ((d & 63) == 0) s_w[d >> 6] = sq;
        __syncthreads();
        float tot = s_w[0] + s_w[1];
        float vn = pooled * rsqrtf(tot + 1e-12f);
        __hip_bfloat16 h = __float2bfloat16(vn);
        pnh[c * D_SZ + d] = h;
        pnl[c * D_SZ + d] = __float2bfloat16(vn - __bfloat162float(h));
    } else {
        __syncthreads();   // matching barrier
    }
}

// Fused: rows 0..2047 = en @ en^T -> sim ; rows 2048..4095 = pn @ en^T -> cosm.
__global__ __launch_bounds__(256) void k_gemm_mfma(const __hip_bfloat16* __restrict__ enh_p,
                                                   const __hip_bfloat16* __restrict__ enl_p,
                                                   const __hip_bfloat16* __restrict__ pnh_p,
                                                   const __hip_bfloat16* __restrict__ pnl_p,
                                                   float* __restrict__ sim,
                                                   float* __restrict__ cosm) {
    extern __shared__ char smem[];
    char* As = smem;           // 64 rows * 512B: kbyte 0..255 = hi, 256..511 = lo
    char* Bs = smem + 32768;
    const int tid = threadIdx.x;
    const __hip_bfloat16* Ah;
    const __hip_bfloat16* Al;
    float* Out;
    int rb;
    if (blockIdx.y < 32) { Ah = enh_p; Al = enl_p; Out = sim;  rb = blockIdx.y << 6; }
    else                 { Ah = pnh_p; Al = pnl_p; Out = cosm; rb = (blockIdx.y - 32) << 6; }
    const int cb = blockIdx.x << 6;
    {
        int r = tid >> 2;
        int c0 = (tid & 3) << 5;
        int sw = (r & 7) << 4;
#pragma unroll
        for (int j = 0; j < 4; ++j) {
            int c = c0 + (j << 3);
            uint4 vh = *(const uint4*)&Ah[(rb + r) * D_SZ + c];
            *(uint4*)(As + r * 512 + ((2 * c) ^ sw)) = vh;
            uint4 vl = *(const uint4*)&Al[(rb + r) * D_SZ + c];
            *(uint4*)(As + r * 512 + ((512 + 2 * c) ^ sw) - 256) = vl;
            uint4 wh = *(const uint4*)&enh_p[(cb + r) * D_SZ + c];
            *(uint4*)(Bs + r * 512 + ((2 * c) ^ sw)) = wh;
            uint4 wl = *(const uint4*)&enl_p[(cb + r) * D_SZ + c];
            *(uint4*)(Bs + r * 512 + ((512 + 2 * c) ^ sw) - 256) = wl;
        }
    }
    __syncthreads();
    const int w = tid >> 6, lane = tid & 63;
    const int wr = (w >> 1) << 5;
    const int wc = (w & 1) << 5;
    const int lrow = lane & 15;
    const int lk = (lane >> 4) << 4;
    int ar0 = wr + lrow, ar1 = wr + 16 + lrow;
    int br0 = wc + lrow, br1 = wc + 16 + lrow;
    const char* pa0 = As + ar0 * 512; const int swa0 = (ar0 & 7) << 4;
    const char* pa1 = As + ar1 * 512; const int swa1 = (ar1 & 7) << 4;
    const char* pb0 = Bs + br0 * 512; const int swb0 = (br0 & 7) << 4;
    const char* pb1 = Bs + br1 * 512; const int swb1 = (br1 & 7) << 4;
    f32x4 acc00 = {0.f, 0.f, 0.f, 0.f};
    f32x4 acc01 = acc00, acc10 = acc00, acc11 = acc00;
#pragma unroll
    for (int term = 0; term < 3; ++term) {
        const int ao = (term == 2) ? 256 : 0;   // A: hi,hi,lo
        const int bo = (term == 1) ? 256 : 0;   // B: hi,lo,hi
#pragma unroll
        for (int kk = 0; kk < 4; ++kk) {
            const int ka = ao + (kk << 6) + lk;
            const int kb = bo + (kk << 6) + lk;
            short8 a0 = *(const short8*)(pa0 + ((ka & 0x100) | ((ka & 0xFF) ^ swa0)));
            short8 a1 = *(const short8*)(pa1 + ((ka & 0x100) | ((ka & 0xFF) ^ swa1)));
            short8 b0 = *(const short8*)(pb0 + ((kb & 0x100) | ((kb & 0xFF) ^ swb0)));
            short8 b1 = *(const short8*)(pb1 + ((kb & 0x100) | ((kb & 0xFF) ^ swb1)));
            acc00 = __builtin_amdgcn_mfma_f32_16x16x32_bf16(a0, b0, acc00, 0, 0, 0);
            acc01 = __builtin_amdgcn_mfma_f32_16x16x32_bf16(a0, b1, acc01, 0, 0, 0);
            acc10 = __builtin_amdgcn_mfma_f32_16x16x32_bf16(a1, b0, acc10, 0, 0, 0);
            acc11 = __builtin_amdgcn_mfma_f32_16x16x32_bf16(a1, b1, acc11, 0, 0, 0);
        }
    }
    const int crow = rb + wr + ((lane >> 4) << 2);
    const int ccol = cb + wc + lrow;
#pragma unroll
    for (int r = 0; r < 4; ++r) {
        Out[(crow + r) * C_SZ + ccol]           = acc00[r];
        Out[(crow + r) * C_SZ + ccol + 16]      = acc01[r];
        Out[(crow + 16 + r) * C_SZ + ccol]      = acc10[r];
        Out[(crow + 16 + r) * C_SZ + ccol + 16] = acc11[r];
    }
}

// Two rows per 512-thread block. Idempotent per-row partial[] output.
__global__ __launch_bounds__(512) void k_rank_softmax(const float* __restrict__ sim,
                                                      const float* __restrict__ cosm,
                                                      const int* __restrict__ pos_count,
                                                      const float* __restrict__ tempPtr,
                                                      float* __restrict__ partial) {
    const int i0 = blockIdx.x << 1;
    __shared__ unsigned s_keys[2][C_SZ];          // 16 KB
    __shared__ unsigned short s_idx[2][C_SZ];     // 8 KB
    __shared__ unsigned s_hist[2][C_SZ / 2];      // 8 KB (2x u16 fields per word)
    __shared__ int s_wt[2][8];
    __shared__ float s_reds[2][8];
    __shared__ float s_diag[2];
    const int tid = threadIdx.x;     // 0..511
    const int lane = tid & 63;
    const int w = tid >> 6;          // 0..7
    const int base = tid << 2;       // 4 elems/thread/row
    const float M = 21.0f;
    const float temp = tempPtr[0];

    const bool v0 = pos_count[i0] != 0;
    const bool v1 = pos_count[i0 + 1] != 0;

    float4 sa0 = *(const float4*)&sim[i0 * C_SZ + base];
    float4 sa1 = *(const float4*)&sim[(i0 + 1) * C_SZ + base];
    float4 ca0 = *(const float4*)&cosm[i0 * C_SZ + base];
    float4 ca1 = *(const float4*)&cosm[(i0 + 1) * C_SZ + base];
    {
        uint4 z4 = {0u, 0u, 0u, 0u};
        ((uint4*)s_hist)[tid] = z4;
    }
    float xs0[4] = {sa0.x, sa0.y, sa0.z, sa0.w};
    float xs1[4] = {sa1.x, sa1.y, sa1.z, sa1.w};
    unsigned uk0[4], uk1[4];
    int bk0[4], bk1[4];
#pragma unroll
    for (int e = 0; e < 4; ++e) {
        unsigned u = __float_as_uint(xs0[e]);
        u = (u & 0x80000000u) ? ~u : (u | 0x80000000u);
        if (u == 0x7FFFFFFFu) u = 0x80000000u;
        uk0[e] = u;
        int b = (int)((xs0[e] + 0.5f) * 2047.0f);
        bk0[e] = b < 0 ? 0 : (b > 2047 ? 2047 : b);
        unsigned u1 = __float_as_uint(xs1[e]);
        u1 = (u1 & 0x80000000u) ? ~u1 : (u1 | 0x80000000u);
        if (u1 == 0x7FFFFFFFu) u1 = 0x80000000u;
        uk1[e] = u1;
        int b1 = (int)((xs1[e] + 0.5f) * 2047.0f);
        bk1[e] = b1 < 0 ? 0 : (b1 > 2047 ? 2047 : b1);
    }
    __syncthreads();
    if (v0) {
#pragma unroll
        for (int e = 0; e < 4; ++e)
            atomicAdd(&s_hist[0][bk0[e] >> 1], 1u << ((bk0[e] & 1) << 4));
    }
    if (v1) {
#pragma unroll
        for (int e = 0; e < 4; ++e)
            atomicAdd(&s_hist[1][bk1[e] >> 1], 1u << ((bk1[e] & 1) << 4));
    }
    __syncthreads();
    unsigned w00 = s_hist[0][2 * tid], w01 = s_hist[0][2 * tid + 1];
    unsigned w10 = s_hist[1][2 * tid], w11 = s_hist[1][2 * tid + 1];
    unsigned c00 = w00 & 0xFFFF, c01 = w00 >> 16, c02 = w01 & 0xFFFF, c03 = w01 >> 16;
    unsigned c10 = w10 & 0xFFFF, c11 = w10 >> 16, c12 = w11 & 0xFFFF, c13 = w11 >> 16;
    unsigned sum0 = c00 + c01 + c02 + c03;
    unsigned sum1 = c10 + c11 + c12 + c13;
    int incl0 = (int)sum0, incl1 = (int)sum1;
#pragma unroll
    for (int off = 1; off < 64; off <<= 1) {
        int o0 = __shfl_up(incl0, off);
        int o1 = __shfl_up(incl1, off);
        if (lane >= off) { incl0 += o0; incl1 += o1; }
    }
    if (lane == 63) { s_wt[0][w] = incl0; s_wt[1][w] = incl1; }
    __syncthreads();
    int wb0 = 0, wb1 = 0;
#pragma unroll
    for (int ww = 0; ww < 8; ++ww) {
        wb0 += (ww < w) ? s_wt[0][ww] : 0;
        wb1 += (ww < w) ? s_wt[1][ww] : 0;
    }
    unsigned eb0 = (unsigned)(wb0 + incl0 - (int)sum0);
    unsigned eb1 = (unsigned)(wb1 + incl1 - (int)sum1);
    {
        unsigned e00 = eb0, e01 = eb0 + c00, e02 = eb0 + c00 + c01, e03 = eb0 + c00 + c01 + c02;
        s_hist[0][2 * tid]     = e00 | (e01 << 16);
        s_hist[0][2 * tid + 1] = e02 | (e03 << 16);
        unsigned e10 = eb1, e11 = eb1 + c10, e12 = eb1 + c10 + c11, e13 = eb1 + c10 + c11 + c12;
        s_hist[1][2 * tid]     = e10 | (e11 << 16);
        s_hist[1][2 * tid + 1] = e12 | (e13 << 16);
    }
    __syncthreads();
    if (v0) {
#pragma unroll
        for (int e = 0; e < 4; ++e) {
            int sh = (bk0[e] & 1) << 4;
            unsigned old = atomicAdd(&s_hist[0][bk0[e] >> 1], 1u << sh);
            unsigned pos = (old >> sh) & 0xFFFFu;
            s_keys[0][pos] = uk0[e];
            s_idx[0][pos] = (unsigned short)(base + e);
        }
    }
    if (v1) {
#pragma unroll
        for (int e = 0; e < 4; ++e) {
            int sh = (bk1[e] & 1) << 4;
            unsigned old = atomicAdd(&s_hist[1][bk1[e] >> 1], 1u << sh);
            unsigned pos = (old >> sh) & 0xFFFFu;
            s_keys[1][pos] = uk1[e];
            s_idx[1][pos] = (unsigned short)(base + e);
        }
    }
    __syncthreads();
    float ls0 = 0.f, ls1 = 0.f;
    float cs0[4] = {ca0.x, ca0.y, ca0.z, ca0.w};
    float cs1[4] = {ca1.x, ca1.y, ca1.z, ca1.w};
    if (v0) {
        float lg0[4];
#pragma unroll
        for (int e = 0; e < 4; ++e) {
            int b = bk0[e];
            unsigned endv = (s_hist[0][b >> 1] >> ((b & 1) << 4)) & 0xFFFFu;
            unsigned startv = b ? ((s_hist[0][(b - 1) >> 1] >> (((b - 1) & 1) << 4)) & 0xFFFFu) : 0u;
            unsigned mk = uk0[e];
            int less = 0, eq = 0;
            for (unsigned j = startv; j < endv; ++j) {
                unsigned kj = s_keys[0][j];
                less += (kj < mk) ? 1 : 0;
                eq += (kj == mk) ? 1 : 0;
            }
            if (eq > 1) {
                unsigned myi = (unsigned)(base + e);
                for (unsigned j = startv; j < endv; ++j)
                    if (s_keys[0][j] == mk && (unsigned)s_idx[0][j] < myi) less++;
            }
            int rk = (int)startv + less;
            float den = temp * __logf((float)rk + 2.0f);
            lg0[e] = __fdividef(cs0[e], den);
            ls0 += __expf(lg0[e] - M);
        }
        if ((i0 >> 2) == tid) {
            int ei = i0 & 3;
            float dv = lg0[0];
#pragma unroll
            for (int e = 1; e < 4; ++e) dv = (ei == e) ? lg0[e] : dv;
            s_diag[0] = dv;
        }
    }
    if (v1) {
        float lg1[4];
#pragma unroll
        for (int e = 0; e < 4; ++e) {
            int b = bk1[e];
            unsigned endv = (s_hist[1][b >> 1] >> ((b & 1) << 4)) & 0xFFFFu;
            unsigned startv = b ? ((s_hist[1][(b - 1) >> 1] >> (((b - 1) & 1) << 4)) & 0xFFFFu) : 0u;
            unsigned mk = uk1[e];
            int less = 0, eq = 0;
            for (unsigned j = startv; j < endv; ++j) {
                unsigned kj = s_keys[1][j];
                less += (kj < mk) ? 1 : 0;
                eq += (kj == mk) ? 1 : 0;
            }
            if (eq > 1) {
                unsigned myi = (unsigned)(base + e);
                for (unsigned j = startv; j < endv; ++j)
                    if (s_keys[1][j] == mk && (unsigned)s_idx[1][j] < myi) less++;
            }
            int rk = (int)startv + less;
            float den = temp * __logf((float)rk + 2.0f);
            lg1[e] = __fdividef(cs1[e], den);
            ls1 += __expf(lg1[e] - M);
        }
        if (((i0 + 1) >> 2) == tid) {
            int ei = (i0 + 1) & 3;
            float dv = lg1[0];
#pragma unroll
            for (int e = 1; e < 4; ++e) dv = (ei == e) ? lg1[e] : dv;
            s_diag[1] = dv;
        }
    }
#pragma unroll
    for (int off = 1; off < 64; off <<= 1) {
        ls0 += __shfl_xor(ls0, off);
        ls1 += __shfl_xor(ls1, off);
    }
    if (lane == 0) { s_reds[0][w] = ls0; s_reds[1][w] = ls1; }
    __syncthreads();
    if (tid == 0) {
        float t0 = 0.f, t1 = 0.f;
#pragma unroll
        for (int ww = 0; ww < 8; ++ww) { t0 += s_reds[0][ww]; t1 += s_reds[1][ww]; }
        float lp0 = v0 ? -(s_diag[0] - M - logf(t0)) : 0.f;
        float lp1 = v1 ? -(s_diag[1] - M - logf(t1)) : 0.f;
        partial[2 * i0]     = lp0;
        partial[2 * i0 + 1] = v0 ? 1.f : 0.f;
        partial[2 * i0 + 2] = lp1;
        partial[2 * i0 + 3] = v1 ? 1.f : 0.f;
    }
}

// reduce per-row partials -> mean
__global__ __launch_bounds__(256) void k_final(const float* __restrict__ partial,
                                               float* __restrict__ out) {
    const int t = threadIdx.x;
    const int lane = t & 63;
    const int w = t >> 6;
    __shared__ float s_lp[4], s_nv[4];
    float lp = 0.f, nv = 0.f;
#pragma unroll
    for (int k = 0; k < 8; ++k) {
        float2 p = ((const float2*)partial)[k * 256 + t];
        lp += p.x; nv += p.y;
    }
#pragma unroll
    for (int off = 1; off < 64; off <<= 1) {
        lp += __shfl_xor(lp, off);
        nv += __shfl_xor(nv, off);
    }
    if (lane == 0) { s_lp[w] = lp; s_nv[w] = nv; }
    __syncthreads();
    if (t == 0) {
        float slp = s_lp[0] + s_lp[1] + s_lp[2] + s_lp[3];
        float snv = s_nv[0] + s_nv[1] + s_nv[2] + s_nv[3];
        out[0] = slp / fmaxf(snv, 1.0f);
    }
}

extern "C" void kernel_launch(void* const* d_in, const int* in_sizes, int n_in,
                              void* d_out, int out_size, void* d_ws, size_t ws_size,
                              hipStream_t stream) {
    const float* output    = (const float*)d_in[0];
    const float* class_emb = (const float*)d_in[1];
    const float* targets   = (const float*)d_in[2];
    const float* tempPtr   = (const float*)d_in[3];
    float* out = (float*)d_out;
    char* ws = (char*)d_ws;

    int*   pos_count = (int*)(ws + 0);
    int*   pos_list  = (int*)(ws + 8448);
    __hip_bfloat16* pnh = (__hip_bfloat16*)(ws + 2105600);
    __hip_bfloat16* pnl = (__hip_bfloat16*)(ws + 2629888);
    __hip_bfloat16* enh = (__hip_bfloat16*)(ws + 3154176);
    __hip_bfloat16* enl = (__hip_bfloat16*)(ws + 3678464);
    float* sim       = (float*)(ws + 4210944);
    float* cosm      = (float*)(ws + 20988160);
    float* partial   = (float*)(ws + 37765376);
    // measurement scratch (dup scan; pc2 zeroed by k_pre so behavior matches)
    int*   pc2 = (int*)(ws + 41943040);
    int*   pl2 = (int*)(ws + 41951488);
    __hip_bfloat16* enh2 = (__hip_bfloat16*)(ws + 44048384);
    __hip_bfloat16* enl2 = (__hip_bfloat16*)(ws + 44572672);

    k_pre<<<8, 256, 0, stream>>>((unsigned*)ws, (unsigned*)pc2);
    k_scan<<<SCAN_BLOCKS + C_SZ / 2, 256, 0, stream>>>(targets, class_emb,
                                                       pos_count, pos_list, enh, enl);
    k_pool<<<C_SZ, 256, 0, stream>>>(output, pos_count, pos_list, pnh, pnl);
    dim3 g(C_SZ / 64, 2 * C_SZ / 64);
    k_gemm_mfma<<<g, 256, 65536, stream>>>(enh, enl, pnh, pnl, sim, cosm);
    k_rank_softmax<<<C_SZ / 2, 512, 0, stream>>>(sim, cosm, pos_count, tempPtr, partial);
    // MEASUREMENT: duplicate scan into scratch. total - 94 ~= scan(warm) + gap.
    k_scan<<<SCAN_BLOCKS + C_SZ / 2, 256, 0, stream>>>(targets, class_emb,
                                                       pc2, pl2, enh2, enl2);
    k_final<<<1, 256, 0, stream>>>(partial, out);
}

// Round 17
// 93.560 us; speedup vs baseline: 1.2667x; 1.2667x over previous
//
#include <hip/hip_runtime.h>
#include <hip/hip_bf16.h>
#include <math.h>

#define B_SZ 16384
#define C_SZ 2048
#define D_SZ 128
#define MAXP 256
#define SCAN_BLOCKS 4096

typedef float f32x4 __attribute__((ext_vector_type(4)));
typedef short short8 __attribute__((ext_vector_type(8)));

// ---- workspace layout (bytes) ----
// 0        : pos_count[C]     int   (8192)
// 8448     : pos_list[C*MAXP] int   (2 MB)   -> 2,105,600
// 2105600  : pnh [C*D] bf16 (512KB) -> 2,629,888
// 2629888  : pnl [C*D] bf16 (512KB) -> 3,154,176
// 3154176  : enh [C*D] bf16 (512KB) -> 3,678,464
// 3678464  : enl [C*D] bf16 (512KB) -> 4,202,752
// 4210944  : sim[C*C] f32 (16MB)    -> 20,988,160
// 20988160 : cosm[C*C] f32 (16MB)   -> 37,765,376
// 37765376 : partial[C*2] f32 (16KB)

__global__ __launch_bounds__(256) void k_pre(unsigned* __restrict__ zr) {
    int t = blockIdx.x * blockDim.x + threadIdx.x;
    if (t < C_SZ) zr[t] = 0u;
}

// blocks 0..4095: scan targets -> pos lists (two-phase branchless: streaming
// presence-mask pass at full HBM rate, then rare atomic+store).
// blocks 4096+: L2-normalize class_emb (hides under the HBM-bound stream).
__global__ __launch_bounds__(256) void k_scan(const float* __restrict__ targets,
                                              const float* __restrict__ class_emb,
                                              int* __restrict__ pos_count,
                                              int* __restrict__ pos_list,
                                              __hip_bfloat16* __restrict__ enh,
                                              __hip_bfloat16* __restrict__ enl) {
    const int bid = blockIdx.x;
    if (bid >= SCAN_BLOCKS) {
        const int g = threadIdx.x >> 7;        // 0..1 class within block
        const int d = threadIdx.x & 127;
        const int c = ((bid - SCAN_BLOCKS) << 1) + g;
        __shared__ float s_w[2][2];
        float v = class_emb[c * D_SZ + d];
        float sq = v * v;
#pragma unroll
        for (int off = 32; off >= 1; off >>= 1) sq += __shfl_xor(sq, off);
        if ((d & 63) == 0) s_w[g][d >> 6] = sq;
        __syncthreads();
        float tot = s_w[g][0] + s_w[g][1];
        float vn = v * rsqrtf(tot + 1e-12f);
        __hip_bfloat16 h = __float2bfloat16(vn);
        enh[c * D_SZ + d] = h;
        enl[c * D_SZ + d] = __float2bfloat16(vn - __bfloat162float(h));
        return;
    }
    const int tid = bid * 256 + threadIdx.x;          // 0..1048575
    const int stride = SCAN_BLOCKS * 256;             // 1,048,576 float4s
    unsigned mask = 0u;
#pragma unroll
    for (int k = 0; k < 8; ++k) {
        float4 t = ((const float4*)targets)[tid + k * stride];
        unsigned m = (unsigned)(t.x != 0.f)
                   | ((unsigned)(t.y != 0.f) << 1)
                   | ((unsigned)(t.z != 0.f) << 2)
                   | ((unsigned)(t.w != 0.f) << 3);
        mask |= m << (k << 2);
    }
    while (mask) {
        int bit = __builtin_ctz(mask);
        mask &= mask - 1;
        int k = bit >> 2, q = bit & 3;
        int e0 = (tid + k * stride) << 2;
        int b = e0 >> 11;
        int c = (e0 & (C_SZ - 1)) + q;
        int slot = atomicAdd(&pos_count[c], 1);
        if ((unsigned)slot < (unsigned)MAXP) pos_list[c * MAXP + slot] = b;
    }
}

// masked mean pool + L2 norm -> pn(h,l). 256 thr/class, k-loop split in halves.
__global__ __launch_bounds__(256) void k_pool(const float* __restrict__ output,
                                              const int* __restrict__ pos_count,
                                              const int* __restrict__ pos_list,
                                              __hip_bfloat16* __restrict__ pnh,
                                              __hip_bfloat16* __restrict__ pnl) {
    int c = blockIdx.x;
    int d = threadIdx.x & 127;
    int half = threadIdx.x >> 7;
    __shared__ float s_acc[2][128];
    __shared__ float s_cnt[2][128];
    __shared__ float s_w[2];
    int n = pos_count[c];
    if (n > MAXP) n = MAXP;
    float acc = 0.f, cnt = 0.f;
    for (int k = half; k < n; k += 2) {
        int b = pos_list[c * MAXP + k];
        float v = output[b * D_SZ + d];
        acc += v;
        cnt += (v != 0.f) ? 1.f : 0.f;
    }
    s_acc[half][d] = acc;
    s_cnt[half][d] = cnt;
    __syncthreads();
    if (half == 0) {
        acc = s_acc[0][d] + s_acc[1][d];
        cnt = s_cnt[0][d] + s_cnt[1][d];
        float pooled = acc / (cnt + 1e-9f);
        float sq = pooled * pooled;
#pragma unroll
        for (int off = 32; off >= 1; off >>= 1) sq += __shfl_xor(sq, off);
        if ((d & 63) == 0) s_w[d >> 6] = sq;
        __syncthreads();
        float tot = s_w[0] + s_w[1];
        float vn = pooled * rsqrtf(tot + 1e-12f);
        __hip_bfloat16 h = __float2bfloat16(vn);
        pnh[c * D_SZ + d] = h;
        pnl[c * D_SZ + d] = __float2bfloat16(vn - __bfloat162float(h));
    } else {
        __syncthreads();   // matching barrier
    }
}

// Fused: rows 0..2047 = en @ en^T -> sim ; rows 2048..4095 = pn @ en^T -> cosm.
// 64x64 tile, 4 waves (2x2 of 32x32), split-bf16 3-term MFMA, XOR-swizzled LDS.
__global__ __launch_bounds__(256) void k_gemm_mfma(const __hip_bfloat16* __restrict__ enh_p,
                                                   const __hip_bfloat16* __restrict__ enl_p,
                                                   const __hip_bfloat16* __restrict__ pnh_p,
                                                   const __hip_bfloat16* __restrict__ pnl_p,
                                                   float* __restrict__ sim,
                                                   float* __restrict__ cosm) {
    extern __shared__ char smem[];
    char* As = smem;           // 64 rows * 512B: kbyte 0..255 = hi, 256..511 = lo
    char* Bs = smem + 32768;
    const int tid = threadIdx.x;
    const __hip_bfloat16* Ah;
    const __hip_bfloat16* Al;
    float* Out;
    int rb;
    if (blockIdx.y < 32) { Ah = enh_p; Al = enl_p; Out = sim;  rb = blockIdx.y << 6; }
    else                 { Ah = pnh_p; Al = pnl_p; Out = cosm; rb = (blockIdx.y - 32) << 6; }
    const int cb = blockIdx.x << 6;
    {
        int r = tid >> 2;
        int c0 = (tid & 3) << 5;
        int sw = (r & 7) << 4;
#pragma unroll
        for (int j = 0; j < 4; ++j) {
            int c = c0 + (j << 3);
            uint4 vh = *(const uint4*)&Ah[(rb + r) * D_SZ + c];
            *(uint4*)(As + r * 512 + ((2 * c) ^ sw)) = vh;
            uint4 vl = *(const uint4*)&Al[(rb + r) * D_SZ + c];
            *(uint4*)(As + r * 512 + ((512 + 2 * c) ^ sw) - 256) = vl;
            uint4 wh = *(const uint4*)&enh_p[(cb + r) * D_SZ + c];
            *(uint4*)(Bs + r * 512 + ((2 * c) ^ sw)) = wh;
            uint4 wl = *(const uint4*)&enl_p[(cb + r) * D_SZ + c];
            *(uint4*)(Bs + r * 512 + ((512 + 2 * c) ^ sw) - 256) = wl;
        }
    }
    __syncthreads();
    const int w = tid >> 6, lane = tid & 63;
    const int wr = (w >> 1) << 5;
    const int wc = (w & 1) << 5;
    const int lrow = lane & 15;
    const int lk = (lane >> 4) << 4;
    int ar0 = wr + lrow, ar1 = wr + 16 + lrow;
    int br0 = wc + lrow, br1 = wc + 16 + lrow;
    const char* pa0 = As + ar0 * 512; const int swa0 = (ar0 & 7) << 4;
    const char* pa1 = As + ar1 * 512; const int swa1 = (ar1 & 7) << 4;
    const char* pb0 = Bs + br0 * 512; const int swb0 = (br0 & 7) << 4;
    const char* pb1 = Bs + br1 * 512; const int swb1 = (br1 & 7) << 4;
    f32x4 acc00 = {0.f, 0.f, 0.f, 0.f};
    f32x4 acc01 = acc00, acc10 = acc00, acc11 = acc00;
#pragma unroll
    for (int term = 0; term < 3; ++term) {
        const int ao = (term == 2) ? 256 : 0;   // A: hi,hi,lo
        const int bo = (term == 1) ? 256 : 0;   // B: hi,lo,hi
#pragma unroll
        for (int kk = 0; kk < 4; ++kk) {
            const int ka = ao + (kk << 6) + lk;
            const int kb = bo + (kk << 6) + lk;
            short8 a0 = *(const short8*)(pa0 + ((ka & 0x100) | ((ka & 0xFF) ^ swa0)));
            short8 a1 = *(const short8*)(pa1 + ((ka & 0x100) | ((ka & 0xFF) ^ swa1)));
            short8 b0 = *(const short8*)(pb0 + ((kb & 0x100) | ((kb & 0xFF) ^ swb0)));
            short8 b1 = *(const short8*)(pb1 + ((kb & 0x100) | ((kb & 0xFF) ^ swb1)));
            acc00 = __builtin_amdgcn_mfma_f32_16x16x32_bf16(a0, b0, acc00, 0, 0, 0);
            acc01 = __builtin_amdgcn_mfma_f32_16x16x32_bf16(a0, b1, acc01, 0, 0, 0);
            acc10 = __builtin_amdgcn_mfma_f32_16x16x32_bf16(a1, b0, acc10, 0, 0, 0);
            acc11 = __builtin_amdgcn_mfma_f32_16x16x32_bf16(a1, b1, acc11, 0, 0, 0);
        }
    }
    const int crow = rb + wr + ((lane >> 4) << 2);
    const int ccol = cb + wc + lrow;
#pragma unroll
    for (int r = 0; r < 4; ++r) {
        Out[(crow + r) * C_SZ + ccol]           = acc00[r];
        Out[(crow + r) * C_SZ + ccol + 16]      = acc01[r];
        Out[(crow + 16 + r) * C_SZ + ccol]      = acc10[r];
        Out[(crow + 16 + r) * C_SZ + ccol + 16] = acc11[r];
    }
}

// Two rows per 512-thread block: single-pass bucket-rank (packed u16 hist,
// value-linear buckets, exact stable tie-break) -> inline discounted logits ->
// fixed-shift softmax -> diagonal -> per-row partial[] (idempotent).
__global__ __launch_bounds__(512) void k_rank_softmax(const float* __restrict__ sim,
                                                      const float* __restrict__ cosm,
                                                      const int* __restrict__ pos_count,
                                                      const float* __restrict__ tempPtr,
                                                      float* __restrict__ partial) {
    const int i0 = blockIdx.x << 1;
    __shared__ unsigned s_keys[2][C_SZ];          // 16 KB
    __shared__ unsigned short s_idx[2][C_SZ];     // 8 KB
    __shared__ unsigned s_hist[2][C_SZ / 2];      // 8 KB (2x u16 fields per word)
    __shared__ int s_wt[2][8];
    __shared__ float s_reds[2][8];
    __shared__ float s_diag[2];
    const int tid = threadIdx.x;     // 0..511
    const int lane = tid & 63;
    const int w = tid >> 6;          // 0..7
    const int base = tid << 2;       // 4 elems/thread/row
    const float M = 21.0f;
    const float temp = tempPtr[0];

    const bool v0 = pos_count[i0] != 0;
    const bool v1 = pos_count[i0 + 1] != 0;

    float4 sa0 = *(const float4*)&sim[i0 * C_SZ + base];
    float4 sa1 = *(const float4*)&sim[(i0 + 1) * C_SZ + base];
    float4 ca0 = *(const float4*)&cosm[i0 * C_SZ + base];
    float4 ca1 = *(const float4*)&cosm[(i0 + 1) * C_SZ + base];
    {
        uint4 z4 = {0u, 0u, 0u, 0u};
        ((uint4*)s_hist)[tid] = z4;
    }
    float xs0[4] = {sa0.x, sa0.y, sa0.z, sa0.w};
    float xs1[4] = {sa1.x, sa1.y, sa1.z, sa1.w};
    unsigned uk0[4], uk1[4];
    int bk0[4], bk1[4];
#pragma unroll
    for (int e = 0; e < 4; ++e) {
        unsigned u = __float_as_uint(xs0[e]);
        u = (u & 0x80000000u) ? ~u : (u | 0x80000000u);
        if (u == 0x7FFFFFFFu) u = 0x80000000u;
        uk0[e] = u;
        int b = (int)((xs0[e] + 0.5f) * 2047.0f);
        bk0[e] = b < 0 ? 0 : (b > 2047 ? 2047 : b);
        unsigned u1 = __float_as_uint(xs1[e]);
        u1 = (u1 & 0x80000000u) ? ~u1 : (u1 | 0x80000000u);
        if (u1 == 0x7FFFFFFFu) u1 = 0x80000000u;
        uk1[e] = u1;
        int b1 = (int)((xs1[e] + 0.5f) * 2047.0f);
        bk1[e] = b1 < 0 ? 0 : (b1 > 2047 ? 2047 : b1);
    }
    __syncthreads();
    if (v0) {
#pragma unroll
        for (int e = 0; e < 4; ++e)
            atomicAdd(&s_hist[0][bk0[e] >> 1], 1u << ((bk0[e] & 1) << 4));
    }
    if (v1) {
#pragma unroll
        for (int e = 0; e < 4; ++e)
            atomicAdd(&s_hist[1][bk1[e] >> 1], 1u << ((bk1[e] & 1) << 4));
    }
    __syncthreads();
    unsigned w00 = s_hist[0][2 * tid], w01 = s_hist[0][2 * tid + 1];
    unsigned w10 = s_hist[1][2 * tid], w11 = s_hist[1][2 * tid + 1];
    unsigned c00 = w00 & 0xFFFF, c01 = w00 >> 16, c02 = w01 & 0xFFFF, c03 = w01 >> 16;
    unsigned c10 = w10 & 0xFFFF, c11 = w10 >> 16, c12 = w11 & 0xFFFF, c13 = w11 >> 16;
    unsigned sum0 = c00 + c01 + c02 + c03;
    unsigned sum1 = c10 + c11 + c12 + c13;
    int incl0 = (int)sum0, incl1 = (int)sum1;
#pragma unroll
    for (int off = 1; off < 64; off <<= 1) {
        int o0 = __shfl_up(incl0, off);
        int o1 = __shfl_up(incl1, off);
        if (lane >= off) { incl0 += o0; incl1 += o1; }
    }
    if (lane == 63) { s_wt[0][w] = incl0; s_wt[1][w] = incl1; }
    __syncthreads();
    int wb0 = 0, wb1 = 0;
#pragma unroll
    for (int ww = 0; ww < 8; ++ww) {
        wb0 += (ww < w) ? s_wt[0][ww] : 0;
        wb1 += (ww < w) ? s_wt[1][ww] : 0;
    }
    unsigned eb0 = (unsigned)(wb0 + incl0 - (int)sum0);
    unsigned eb1 = (unsigned)(wb1 + incl1 - (int)sum1);
    {
        unsigned e00 = eb0, e01 = eb0 + c00, e02 = eb0 + c00 + c01, e03 = eb0 + c00 + c01 + c02;
        s_hist[0][2 * tid]     = e00 | (e01 << 16);
        s_hist[0][2 * tid + 1] = e02 | (e03 << 16);
        unsigned e10 = eb1, e11 = eb1 + c10, e12 = eb1 + c10 + c11, e13 = eb1 + c10 + c11 + c12;
        s_hist[1][2 * tid]     = e10 | (e11 << 16);
        s_hist[1][2 * tid + 1] = e12 | (e13 << 16);
    }
    __syncthreads();
    if (v0) {
#pragma unroll
        for (int e = 0; e < 4; ++e) {
            int sh = (bk0[e] & 1) << 4;
            unsigned old = atomicAdd(&s_hist[0][bk0[e] >> 1], 1u << sh);
            unsigned pos = (old >> sh) & 0xFFFFu;
            s_keys[0][pos] = uk0[e];
            s_idx[0][pos] = (unsigned short)(base + e);
        }
    }
    if (v1) {
#pragma unroll
        for (int e = 0; e < 4; ++e) {
            int sh = (bk1[e] & 1) << 4;
            unsigned old = atomicAdd(&s_hist[1][bk1[e] >> 1], 1u << sh);
            unsigned pos = (old >> sh) & 0xFFFFu;
            s_keys[1][pos] = uk1[e];
            s_idx[1][pos] = (unsigned short)(base + e);
        }
    }
    __syncthreads();
    float ls0 = 0.f, ls1 = 0.f;
    float cs0[4] = {ca0.x, ca0.y, ca0.z, ca0.w};
    float cs1[4] = {ca1.x, ca1.y, ca1.z, ca1.w};
    if (v0) {
        float lg0[4];
#pragma unroll
        for (int e = 0; e < 4; ++e) {
            int b = bk0[e];
            unsigned endv = (s_hist[0][b >> 1] >> ((b & 1) << 4)) & 0xFFFFu;
            unsigned startv = b ? ((s_hist[0][(b - 1) >> 1] >> (((b - 1) & 1) << 4)) & 0xFFFFu) : 0u;
            unsigned mk = uk0[e];
            int less = 0, eq = 0;
            for (unsigned j = startv; j < endv; ++j) {
                unsigned kj = s_keys[0][j];
                less += (kj < mk) ? 1 : 0;
                eq += (kj == mk) ? 1 : 0;
            }
            if (eq > 1) {
                unsigned myi = (unsigned)(base + e);
                for (unsigned j = startv; j < endv; ++j)
                    if (s_keys[0][j] == mk && (unsigned)s_idx[0][j] < myi) less++;
            }
            int rk = (int)startv + less;
            float den = temp * __logf((float)rk + 2.0f);
            lg0[e] = __fdividef(cs0[e], den);
            ls0 += __expf(lg0[e] - M);
        }
        if ((i0 >> 2) == tid) {
            int ei = i0 & 3;
            float dv = lg0[0];
#pragma unroll
            for (int e = 1; e < 4; ++e) dv = (ei == e) ? lg0[e] : dv;
            s_diag[0] = dv;
        }
    }
    if (v1) {
        float lg1[4];
#pragma unroll
        for (int e = 0; e < 4; ++e) {
            int b = bk1[e];
            unsigned endv = (s_hist[1][b >> 1] >> ((b & 1) << 4)) & 0xFFFFu;
            unsigned startv = b ? ((s_hist[1][(b - 1) >> 1] >> (((b - 1) & 1) << 4)) & 0xFFFFu) : 0u;
            unsigned mk = uk1[e];
            int less = 0, eq = 0;
            for (unsigned j = startv; j < endv; ++j) {
                unsigned kj = s_keys[1][j];
                less += (kj < mk) ? 1 : 0;
                eq += (kj == mk) ? 1 : 0;
            }
            if (eq > 1) {
                unsigned myi = (unsigned)(base + e);
                for (unsigned j = startv; j < endv; ++j)
                    if (s_keys[1][j] == mk && (unsigned)s_idx[1][j] < myi) less++;
            }
            int rk = (int)startv + less;
            float den = temp * __logf((float)rk + 2.0f);
            lg1[e] = __fdividef(cs1[e], den);
            ls1 += __expf(lg1[e] - M);
        }
        if (((i0 + 1) >> 2) == tid) {
            int ei = (i0 + 1) & 3;
            float dv = lg1[0];
#pragma unroll
            for (int e = 1; e < 4; ++e) dv = (ei == e) ? lg1[e] : dv;
            s_diag[1] = dv;
        }
    }
#pragma unroll
    for (int off = 1; off < 64; off <<= 1) {
        ls0 += __shfl_xor(ls0, off);
        ls1 += __shfl_xor(ls1, off);
    }
    if (lane == 0) { s_reds[0][w] = ls0; s_reds[1][w] = ls1; }
    __syncthreads();
    if (tid == 0) {
        float t0 = 0.f, t1 = 0.f;
#pragma unroll
        for (int ww = 0; ww < 8; ++ww) { t0 += s_reds[0][ww]; t1 += s_reds[1][ww]; }
        float lp0 = v0 ? -(s_diag[0] - M - logf(t0)) : 0.f;
        float lp1 = v1 ? -(s_diag[1] - M - logf(t1)) : 0.f;
        partial[2 * i0]     = lp0;
        partial[2 * i0 + 1] = v0 ? 1.f : 0.f;
        partial[2 * i0 + 2] = lp1;
        partial[2 * i0 + 3] = v1 ? 1.f : 0.f;
    }
}

// reduce per-row partials -> mean
__global__ __launch_bounds__(256) void k_final(const float* __restrict__ partial,
                                               float* __restrict__ out) {
    const int t = threadIdx.x;
    const int lane = t & 63;
    const int w = t >> 6;
    __shared__ float s_lp[4], s_nv[4];
    float lp = 0.f, nv = 0.f;
#pragma unroll
    for (int k = 0; k < 8; ++k) {
        float2 p = ((const float2*)partial)[k * 256 + t];
        lp += p.x; nv += p.y;
    }
#pragma unroll
    for (int off = 1; off < 64; off <<= 1) {
        lp += __shfl_xor(lp, off);
        nv += __shfl_xor(nv, off);
    }
    if (lane == 0) { s_lp[w] = lp; s_nv[w] = nv; }
    __syncthreads();
    if (t == 0) {
        float slp = s_lp[0] + s_lp[1] + s_lp[2] + s_lp[3];
        float snv = s_nv[0] + s_nv[1] + s_nv[2] + s_nv[3];
        out[0] = slp / fmaxf(snv, 1.0f);
    }
}

extern "C" void kernel_launch(void* const* d_in, const int* in_sizes, int n_in,
                              void* d_out, int out_size, void* d_ws, size_t ws_size,
                              hipStream_t stream) {
    const float* output    = (const float*)d_in[0];
    const float* class_emb = (const float*)d_in[1];
    const float* targets   = (const float*)d_in[2];
    const float* tempPtr   = (const float*)d_in[3];
    float* out = (float*)d_out;
    char* ws = (char*)d_ws;

    int*   pos_count = (int*)(ws + 0);
    int*   pos_list  = (int*)(ws + 8448);
    __hip_bfloat16* pnh = (__hip_bfloat16*)(ws + 2105600);
    __hip_bfloat16* pnl = (__hip_bfloat16*)(ws + 2629888);
    __hip_bfloat16* enh = (__hip_bfloat16*)(ws + 3154176);
    __hip_bfloat16* enl = (__hip_bfloat16*)(ws + 3678464);
    float* sim       = (float*)(ws + 4210944);
    float* cosm      = (float*)(ws + 20988160);
    float* partial   = (float*)(ws + 37765376);

    k_pre<<<8, 256, 0, stream>>>((unsigned*)ws);
    k_scan<<<SCAN_BLOCKS + C_SZ / 2, 256, 0, stream>>>(targets, class_emb,
                                                       pos_count, pos_list, enh, enl);
    k_pool<<<C_SZ, 256, 0, stream>>>(output, pos_count, pos_list, pnh, pnl);
    dim3 g(C_SZ / 64, 2 * C_SZ / 64);
    k_gemm_mfma<<<g, 256, 65536, stream>>>(enh, enl, pnh, pnl, sim, cosm);
    k_rank_softmax<<<C_SZ / 2, 512, 0, stream>>>(sim, cosm, pos_count, tempPtr, partial);
    k_final<<<1, 256, 0, stream>>>(partial, out);
}